// Round 10
// baseline (19.736 us; speedup 1.0000x reference)
//
#include <hip/hip_runtime.h>
#include <math.h>

#define LOG2E 1.4426950408889634f
#define NW 16   // waves per main block

typedef short short8 __attribute__((ext_vector_type(8)));
typedef float f32x4  __attribute__((ext_vector_type(4)));

__device__ inline unsigned short f2bf(float f) {   // f32 -> bf16 bits, RNE
    unsigned int u = __float_as_uint(f);
    return (unsigned short)((u + 0x7FFFu + ((u >> 16) & 1u)) >> 16);
}

__device__ inline unsigned int cvtpk_bf16(float lo, float hi) {
    unsigned int r;
    asm("v_cvt_pk_bf16_f32 %0, %1, %2" : "=v"(r) : "v"(lo), "v"(hi));
    return r;   // low16 = bf16(lo), high16 = bf16(hi)
}

// Pack kernel: ONE conversion of train data into the B-fragment image.
// Per point P, 4 ushort8 variants (64B):
//   v0: bf16 dims 0-7         v1: bf16 dims 8-15
//   v2: dims 0-6 + n0@slot7   v3: dims 8-14 + n1@slot7
// where n0+n1 = -(0.5*log2e)*||y||^2 (split by halves), padded points get
// -2e30-ish norms so exp2 -> 0.
__global__ __launch_bounds__(256) void kde_pack(
    const float* __restrict__ trainX, short8* __restrict__ packed,
    int nTrain, int nPad)
{
    int P = blockIdx.x * 256 + threadIdx.x;
    if (P >= nPad) return;
    int ci = min(P, nTrain - 1);
    const float4* p = (const float4*)(trainX + (size_t)ci * 16);
    float4 q0 = p[0], q1 = p[1], q2 = p[2], q3 = p[3];
    float inv = (P < nTrain) ? 0.0f : 2e30f;
    float pn0 = (q0.x*q0.x + q0.y*q0.y) + (q0.z*q0.z + q0.w*q0.w)
              + (q1.x*q1.x + q1.y*q1.y) + (q1.z*q1.z + q1.w*q1.w) + inv;
    float pn1 = (q2.x*q2.x + q2.y*q2.y) + (q2.z*q2.z + q2.w*q2.w)
              + (q3.x*q3.x + q3.y*q3.y) + (q3.z*q3.z + q3.w*q3.w) + inv;
    float n0 = -(0.5f * LOG2E) * pn0;
    float n1 = -(0.5f * LOG2E) * pn1;
    unsigned int u0 = cvtpk_bf16(q0.x, q0.y), u1 = cvtpk_bf16(q0.z, q0.w);
    unsigned int u2 = cvtpk_bf16(q1.x, q1.y), u3 = cvtpk_bf16(q1.z, q1.w);
    unsigned int u4 = cvtpk_bf16(q2.x, q2.y), u5 = cvtpk_bf16(q2.z, q2.w);
    unsigned int u6 = cvtpk_bf16(q3.x, q3.y), u7 = cvtpk_bf16(q3.z, q3.w);
    unsigned int u3n = cvtpk_bf16(q1.z, n0),  u7n = cvtpk_bf16(q3.z, n1);
    union { unsigned int u[4]; short8 s; } b0, b1, b2, b3;
    b0.u[0]=u0; b0.u[1]=u1; b0.u[2]=u2; b0.u[3]=u3;
    b1.u[0]=u4; b1.u[1]=u5; b1.u[2]=u6; b1.u[3]=u7;
    b2.u[0]=u0; b2.u[1]=u1; b2.u[2]=u2; b2.u[3]=u3n;
    b3.u[0]=u4; b3.u[1]=u5; b3.u[2]=u6; b3.u[3]=u7n;
    short8* o = packed + (size_t)P * 4;
    o[0] = b0.s; o[1] = b1.s; o[2] = b2.s; o[3] = b3.s;
}

// Main: 256 blocks x 1024 threads (16 waves), NO bulk LDS -> 2 blocks/CU
// (8 waves/SIMD). Block owns 16 test rows; waves partition train tiles.
// Inner loop per 16-pt tile: 1 global dwordx4 (L2-resident packed image),
// 1 mfma_16x16x32_bf16 with invariant C=nxv, 4 exp2, 4 adds. 4-deep unroll.
__global__ __launch_bounds__(1024, 8) void kde_main(
    const float* __restrict__ testX, const short8* __restrict__ packed,
    float* __restrict__ out, int nTest, int tpw, float Z)
{
    const int tid  = threadIdx.x;
    const int lane = tid & 63;
    const int w    = tid >> 6;            // wave 0..15
    const int g    = lane >> 4;
    const int l4   = lane & 15;
    const int h    = g & 1;
    const int rowBase = blockIdx.x * 16;

    __shared__ float red[NW][16];

    // ---- A fragment: rows rowBase..+15, [x_hi | x_lo], slots 23/31 = 1.0 ----
    const int m = min(rowBase + l4, nTest - 1);
    const float4* xp = (const float4*)(testX + (size_t)m * 16);
    float4 x0 = xp[0], x1 = xp[1], x2 = xp[2], x3 = xp[3];
    float xs[16] = {x0.x,x0.y,x0.z,x0.w, x1.x,x1.y,x1.z,x1.w,
                    x2.x,x2.y,x2.z,x2.w, x3.x,x3.y,x3.z,x3.w};
    #pragma unroll
    for (int i = 0; i < 16; ++i) xs[i] *= LOG2E;
    float xn = 0.0f;
    #pragma unroll
    for (int i = 0; i < 16; ++i) xn = fmaf(xs[i], xs[i], xn);
    xn *= 0.5f / LOG2E;                   // 0.5*log2e*||x||^2 of row rowBase+l4

    short8 afrag;
    #pragma unroll
    for (int i = 0; i < 8; ++i) {
        float fx = xs[h * 8 + i];
        unsigned short hb = f2bf(fx);
        float hf = __uint_as_float((unsigned int)hb << 16);
        unsigned short lb = f2bf(fx - hf);
        afrag[i] = (short)((g < 2) ? hb : lb);   // k<16: hi, k>=16: lo
    }
    if (g >= 2) afrag[7] = (short)0x3F80;        // bf16(1.0) at k=23 / k=31

    f32x4 nxv;                                    // invariant MFMA C operand
    #pragma unroll
    for (int r = 0; r < 4; ++r)
        nxv[r] = -__shfl(xn, (lane & 48) + g * 4 + r);

    // ---- this wave's train tiles, read directly from packed image ----
    const short8* pk = packed + (size_t)w * tpw * 64 + (l4 * 4 + g);

    float rsA[4] = {0,0,0,0}, rsB[4] = {0,0,0,0};
    for (int t = 0; t < tpw; t += 4) {
        short8 b0 = pk[(size_t)(t+0) * 64];
        short8 b1 = pk[(size_t)(t+1) * 64];
        short8 b2 = pk[(size_t)(t+2) * 64];
        short8 b3 = pk[(size_t)(t+3) * 64];
        f32x4 c0 = __builtin_amdgcn_mfma_f32_16x16x32_bf16(afrag, b0, nxv, 0,0,0);
        f32x4 c1 = __builtin_amdgcn_mfma_f32_16x16x32_bf16(afrag, b1, nxv, 0,0,0);
        f32x4 c2 = __builtin_amdgcn_mfma_f32_16x16x32_bf16(afrag, b2, nxv, 0,0,0);
        f32x4 c3 = __builtin_amdgcn_mfma_f32_16x16x32_bf16(afrag, b3, nxv, 0,0,0);
        #pragma unroll
        for (int r = 0; r < 4; ++r) {
            rsA[r] += __builtin_amdgcn_exp2f(c0[r]);
            rsB[r] += __builtin_amdgcn_exp2f(c1[r]);
            rsA[r] += __builtin_amdgcn_exp2f(c2[r]);
            rsB[r] += __builtin_amdgcn_exp2f(c3[r]);
        }
    }

    // Reduce across the 16 columns (low-4 lane bits).
    float rs0 = rsA[0] + rsB[0], rs1 = rsA[1] + rsB[1];
    float rs2 = rsA[2] + rsB[2], rs3 = rsA[3] + rsB[3];
    #pragma unroll
    for (int off = 1; off <= 8; off <<= 1) {
        rs0 += __shfl_xor(rs0, off);
        rs1 += __shfl_xor(rs1, off);
        rs2 += __shfl_xor(rs2, off);
        rs3 += __shfl_xor(rs3, off);
    }
    if (l4 == 0) {
        red[w][g * 4 + 0] = rs0;
        red[w][g * 4 + 1] = rs1;
        red[w][g * 4 + 2] = rs2;
        red[w][g * 4 + 3] = rs3;
    }
    __syncthreads();

    if (tid < 16) {
        float s = 0.0f;
        #pragma unroll
        for (int k = 0; k < NW; ++k) s += red[k][tid];
        const int row = rowBase + tid;
        if (row < nTest) out[row] = __logf(s) - Z;
    }
}

extern "C" void kernel_launch(void* const* d_in, const int* in_sizes, int n_in,
                              void* d_out, int out_size, void* d_ws, size_t ws_size,
                              hipStream_t stream) {
    const float* testX  = (const float*)d_in[0];
    const float* trainX = (const float*)d_in[1];
    float* out = (float*)d_out;

    const int D = 16;
    const int nTest  = in_sizes[0] / D;   // 4096
    const int nTrain = in_sizes[1] / D;   // 8192

    const float Z = 0.5f * (float)D * logf(2.0f * (float)M_PI) + logf((float)nTrain);

    // tiles per wave (multiple of 4), padded point count.
    int tiles = (nTrain + 15) / 16;
    int tpw   = (tiles + NW - 1) / NW;
    tpw = (tpw + 3) & ~3;
    int nPad = NW * tpw * 16;             // 8192 at bench size

    short8* packed = (short8*)d_ws;       // nPad * 64B  (512 KB) <= ws_size

    kde_pack<<<(nPad + 255) / 256, 256, 0, stream>>>(trainX, packed, nTrain, nPad);

    const int grid = (nTest + 15) / 16;   // 256 blocks, 16 rows each
    kde_main<<<grid, 1024, 0, stream>>>(testX, packed, out, nTest, tpw, Z);
}

// Round 11
// 18.148 us; speedup vs baseline: 1.0875x; 1.0875x over previous
//
#include <hip/hip_runtime.h>
#include <math.h>

#define LOG2E 1.4426950408889634f
#define NW 16   // waves per block
#define CH 64   // train points staged per chunk per wave

typedef short short8 __attribute__((ext_vector_type(8)));
typedef float f32x4  __attribute__((ext_vector_type(4)));

__device__ inline unsigned short f2bf(float f) {   // f32 -> bf16 bits, RNE
    unsigned int u = __float_as_uint(f);
    return (unsigned short)((u + 0x7FFFu + ((u >> 16) & 1u)) >> 16);
}

__device__ inline unsigned int cvtpk_bf16(float lo, float hi) {
    unsigned int r;
    asm("v_cvt_pk_bf16_f32 %0, %1, %2" : "=v"(r) : "v"(lo), "v"(hi));
    return r;   // low16 = bf16(lo), high16 = bf16(hi)
}

// ONE dispatch. 256 blocks x 1024 threads (16 waves), LDS 65KB ->
// 2 blocks/CU (8 waves/SIMD, VGPR capped at 64). Block owns 16 test rows;
// waves partition train (512 pts = 8 chunks of 64). Each wave stages its
// chunk into PRIVATE 4KB LDS as the packed B-fragment image (4 variants/pt:
// dims0-7, dims8-15, dims0-6+norm0@7, dims8-14+norm1@7; slot-swizzled).
// Pipeline: load(c+1) || inner(c) || write(c+1); no barriers in loop.
// Inner per 16-pt tile: 1 ds_read_b128 + 1 mfma_16x16x32_bf16 (invariant
// C = -testnorm) + 4 exp2 + 4 add.
__global__ __launch_bounds__(1024, 8) void kde_fused(
    const float* __restrict__ testX, const float* __restrict__ trainX,
    float* __restrict__ out, int nTest, int nTrain, float Z)
{
    const int tid  = threadIdx.x;
    const int lane = tid & 63;
    const int w    = tid >> 6;            // wave 0..15
    const int g    = lane >> 4;
    const int l4   = lane & 15;
    const int h    = g & 1;
    const int rowBase = blockIdx.x * 16;

    __shared__ short8 stage[NW * CH * 4];   // 64 KB
    __shared__ float  red[NW][16];

    // ---- A fragment: rows rowBase..+15, [x_hi | x_lo], slots 23/31 = 1.0 ----
    const int m = min(rowBase + l4, nTest - 1);
    const float4* xp = (const float4*)(testX + (size_t)m * 16);
    float4 x0 = xp[0], x1 = xp[1], x2 = xp[2], x3 = xp[3];
    float xs[16] = {x0.x,x0.y,x0.z,x0.w, x1.x,x1.y,x1.z,x1.w,
                    x2.x,x2.y,x2.z,x2.w, x3.x,x3.y,x3.z,x3.w};
    #pragma unroll
    for (int i = 0; i < 16; ++i) xs[i] *= LOG2E;
    float xn = 0.0f;
    #pragma unroll
    for (int i = 0; i < 16; ++i) xn = fmaf(xs[i], xs[i], xn);
    xn *= 0.5f / LOG2E;                   // 0.5*log2e*||x||^2 of row rowBase+l4

    short8 afrag;
    #pragma unroll
    for (int i = 0; i < 8; ++i) {
        float fx = xs[h * 8 + i];
        unsigned short hb = f2bf(fx);
        float hf = __uint_as_float((unsigned int)hb << 16);
        unsigned short lb = f2bf(fx - hf);
        afrag[i] = (short)((g < 2) ? hb : lb);   // k<16: hi, k>=16: lo
    }
    if (g >= 2) afrag[7] = (short)0x3F80;        // bf16(1.0) at k=23 / k=31

    f32x4 nxv;                                    // invariant MFMA C operand
    #pragma unroll
    for (int r = 0; r < 4; ++r)
        nxv[r] = -__shfl(xn, (lane & 48) + g * 4 + r);

    // ---- wave's train slice / chunking ----
    const int perWave = ((nTrain + NW * CH - 1) / (NW * CH)) * CH;
    const int nch  = perWave / CH;
    const int tb   = w * perWave;
    const int nMax = nTrain - 1;

    // LDS addressing (short8 units).
    const int vlane  = (g + l4 + (l4 >> 2)) & 3;           // read slot
    const int rdbase = (w * CH + l4) * 4 + vlane;          // + t*64 per tile
    const int sw  = lane + (lane >> 2);
    const int sl0 = (0 + sw) & 3, sl1 = (1 + sw) & 3;
    const int sl2 = (2 + sw) & 3, sl3 = (3 + sw) & 3;
    const int wrp = (w * CH + lane) * 4;

    float4 q0, q1, q2, q3; float inv;
    auto LOADPT = [&](int c) {                   // lane stages point c*64+lane
        int gi = tb + c * CH + lane;
        int ci = min(gi, nMax);
        const float4* p = (const float4*)(trainX + (size_t)ci * 16);
        q0 = p[0]; q1 = p[1]; q2 = p[2]; q3 = p[3];
        inv = (gi <= nMax) ? 0.0f : 2e30f;
    };
    auto WRITEPT = [&]() {
        float pn0 = ((q0.x*q0.x + q0.y*q0.y) + (q0.z*q0.z + q0.w*q0.w))
                  + ((q1.x*q1.x + q1.y*q1.y) + (q1.z*q1.z + q1.w*q1.w)) + inv;
        float pn1 = ((q2.x*q2.x + q2.y*q2.y) + (q2.z*q2.z + q2.w*q2.w))
                  + ((q3.x*q3.x + q3.y*q3.y) + (q3.z*q3.z + q3.w*q3.w)) + inv;
        float n0 = -(0.5f * LOG2E) * pn0;
        float n1 = -(0.5f * LOG2E) * pn1;
        unsigned int u0 = cvtpk_bf16(q0.x, q0.y), u1 = cvtpk_bf16(q0.z, q0.w);
        unsigned int u2 = cvtpk_bf16(q1.x, q1.y), u3 = cvtpk_bf16(q1.z, q1.w);
        unsigned int u4 = cvtpk_bf16(q2.x, q2.y), u5 = cvtpk_bf16(q2.z, q2.w);
        unsigned int u6 = cvtpk_bf16(q3.x, q3.y), u7 = cvtpk_bf16(q3.z, q3.w);
        unsigned int u3n = cvtpk_bf16(q1.z, n0),  u7n = cvtpk_bf16(q3.z, n1);
        union { unsigned int u[4]; short8 s; } b0, b1, b2, b3;
        b0.u[0]=u0; b0.u[1]=u1; b0.u[2]=u2; b0.u[3]=u3;    // dims 0-7
        b1.u[0]=u4; b1.u[1]=u5; b1.u[2]=u6; b1.u[3]=u7;    // dims 8-15
        b2.u[0]=u0; b2.u[1]=u1; b2.u[2]=u2; b2.u[3]=u3n;   // dims 0-6 + n0
        b3.u[0]=u4; b3.u[1]=u5; b3.u[2]=u6; b3.u[3]=u7n;   // dims 8-14 + n1
        stage[wrp + sl0] = b0.s;
        stage[wrp + sl1] = b1.s;
        stage[wrp + sl2] = b2.s;
        stage[wrp + sl3] = b3.s;
    };

    float rsA[4] = {0,0,0,0}, rsB[4] = {0,0,0,0};
    auto INNER = [&]() {
        #pragma unroll
        for (int t = 0; t < CH / 16; ++t) {
            short8 bf = stage[rdbase + t * 64];
            f32x4 c = __builtin_amdgcn_mfma_f32_16x16x32_bf16(afrag, bf, nxv, 0,0,0);
            if (t & 1) {
                rsB[0] += __builtin_amdgcn_exp2f(c[0]);
                rsB[1] += __builtin_amdgcn_exp2f(c[1]);
                rsB[2] += __builtin_amdgcn_exp2f(c[2]);
                rsB[3] += __builtin_amdgcn_exp2f(c[3]);
            } else {
                rsA[0] += __builtin_amdgcn_exp2f(c[0]);
                rsA[1] += __builtin_amdgcn_exp2f(c[1]);
                rsA[2] += __builtin_amdgcn_exp2f(c[2]);
                rsA[3] += __builtin_amdgcn_exp2f(c[3]);
            }
        }
    };

    // Pipeline: load(c+1) || inner(c) || write(c+1). Wave-private LDS +
    // in-order per-wave DS ops -> no barriers needed.
    LOADPT(0);
    WRITEPT();
    for (int c = 0; c < nch - 1; ++c) {
        LOADPT(c + 1);     // global loads in flight during INNER
        INNER();           // consume chunk c from LDS
        WRITEPT();         // stage chunk c+1 (waits vmcnt, after INNER reads)
    }
    INNER();               // last chunk

    // Reduce across the 16 columns (low-4 lane bits).
    float rs0 = rsA[0] + rsB[0], rs1 = rsA[1] + rsB[1];
    float rs2 = rsA[2] + rsB[2], rs3 = rsA[3] + rsB[3];
    #pragma unroll
    for (int off = 1; off <= 8; off <<= 1) {
        rs0 += __shfl_xor(rs0, off);
        rs1 += __shfl_xor(rs1, off);
        rs2 += __shfl_xor(rs2, off);
        rs3 += __shfl_xor(rs3, off);
    }
    if (l4 == 0) {
        red[w][g * 4 + 0] = rs0;
        red[w][g * 4 + 1] = rs1;
        red[w][g * 4 + 2] = rs2;
        red[w][g * 4 + 3] = rs3;
    }
    __syncthreads();

    if (tid < 16) {
        float s = 0.0f;
        #pragma unroll
        for (int k = 0; k < NW; ++k) s += red[k][tid];
        const int row = rowBase + tid;
        if (row < nTest) out[row] = __logf(s) - Z;
    }
}

extern "C" void kernel_launch(void* const* d_in, const int* in_sizes, int n_in,
                              void* d_out, int out_size, void* d_ws, size_t ws_size,
                              hipStream_t stream) {
    const float* testX  = (const float*)d_in[0];
    const float* trainX = (const float*)d_in[1];
    float* out = (float*)d_out;

    const int D = 16;
    const int nTest  = in_sizes[0] / D;   // 4096
    const int nTrain = in_sizes[1] / D;   // 8192

    const float Z = 0.5f * (float)D * logf(2.0f * (float)M_PI) + logf((float)nTrain);

    const int grid = (nTest + 15) / 16;   // 256 blocks, 16 rows each
    kde_fused<<<grid, 1024, 0, stream>>>(testX, trainX, out, nTest, nTrain, Z);
}